// Round 10
// baseline (11294.478 us; speedup 1.0000x reference)
//
#include <hip/hip_runtime.h>
#include <stdint.h>

// Problem dims (fixed by reference)
#define BB 512      // batch
#define SS 256      // seq
#define EE 128      // embed
#define HH 128      // hidden
#define TT 128      // decode steps
#define G4 512      // 4*H

#define NEG_INF_F (-1e30f)
#define TINY_F32  1.17549435e-38f

typedef float v2f __attribute__((ext_vector_type(2)));

// ---------------- threefry2x32 (JAX-exact, 20 rounds) ----------------
__device__ __forceinline__ uint32_t rotl32(uint32_t v, int r){ return (v<<r)|(v>>(32-r)); }

__device__ __forceinline__ void threefry2x32(uint32_t k0, uint32_t k1,
                                             uint32_t c0, uint32_t c1,
                                             uint32_t* o0, uint32_t* o1){
  uint32_t ks2 = k0 ^ k1 ^ 0x1BD11BDAu;
  uint32_t x0 = c0 + k0;
  uint32_t x1 = c1 + k1;
#define TF_R(rr) { x0 += x1; x1 = rotl32(x1, rr); x1 ^= x0; }
  TF_R(13) TF_R(15) TF_R(26) TF_R(6)
  x0 += k1; x1 += ks2 + 1u;
  TF_R(17) TF_R(29) TF_R(16) TF_R(24)
  x0 += ks2; x1 += k0 + 2u;
  TF_R(13) TF_R(15) TF_R(26) TF_R(6)
  x0 += k0; x1 += k1 + 3u;
  TF_R(17) TF_R(29) TF_R(16) TF_R(24)
  x0 += k1; x1 += ks2 + 4u;
  TF_R(13) TF_R(15) TF_R(26) TF_R(6)
  x0 += ks2; x1 += k0 + 5u;
#undef TF_R
  *o0 = x0; *o1 = x1;
}

// ---------------- XLA CPU f32 tanh expansion (scalar) ----------------
__device__ __forceinline__ float xla_tanhf(float x){
#pragma clang fp contract(off)
  float ax = fabsf(x);
  float xc = fminf(fmaxf(x, -9.0f), 9.0f);
  float x2 = xc*xc;
  float num = -2.76076847742355e-16f;
  num = x2*num + 2.00018790482477e-13f;
  num = x2*num + -8.60467152213735e-11f;
  num = x2*num + 5.12229709037114e-08f;
  num = x2*num + 1.48572235717979e-05f;
  num = x2*num + 6.37261928875436e-04f;
  num = x2*num + 4.89352455891786e-03f;
  num = xc*num;
  float den = 1.19825839466702e-06f;
  den = x2*den + 1.18534705686654e-04f;
  den = x2*den + 2.26843463243900e-03f;
  den = x2*den + 4.89352518554385e-03f;
  return (ax < 4e-4f) ? x : (num/den);
}

__device__ __forceinline__ float xla_sigmoidf(float x){
#pragma clang fp contract(off)
  return 0.5f + 0.5f * xla_tanhf(0.5f * x);
}

// ---------------- packed-pair tanh: identical per-element IEEE ops ----------------
__device__ __forceinline__ v2f splat2(float c){ v2f r; r.x = c; r.y = c; return r; }

__device__ __forceinline__ v2f xla_tanh2(v2f x){
#pragma clang fp contract(off)
  v2f xc;
  xc.x = fminf(fmaxf(x.x, -9.0f), 9.0f);
  xc.y = fminf(fmaxf(x.y, -9.0f), 9.0f);
  v2f x2 = xc*xc;
  v2f num = splat2(-2.76076847742355e-16f);
  num = x2*num + splat2( 2.00018790482477e-13f);
  num = x2*num + splat2(-8.60467152213735e-11f);
  num = x2*num + splat2( 5.12229709037114e-08f);
  num = x2*num + splat2( 1.48572235717979e-05f);
  num = x2*num + splat2( 6.37261928875436e-04f);
  num = x2*num + splat2( 4.89352455891786e-03f);
  num = xc*num;
  v2f den = splat2( 1.19825839466702e-06f);
  den = x2*den + splat2( 1.18534705686654e-04f);
  den = x2*den + splat2( 2.26843463243900e-03f);
  den = x2*den + splat2( 4.89352518554385e-03f);
  v2f r;
  r.x = num.x/den.x;
  r.y = num.y/den.y;
  r.x = (fabsf(x.x) < 4e-4f) ? x.x : r.x;
  r.y = (fabsf(x.y) < 4e-4f) ? x.y : r.y;
  return r;
}

// 4 elements. f64 accumulate via explicit fma(): products are f32-origin
// (24b x 24b mantissa < 53b) -> exact -> fma == mul+add bit-identically.
__device__ __forceinline__ void quad_acc(double& acc, const float4 q, const float4 g,
                                         float e0, float e1, float e2, float e3){
#pragma clang fp contract(off)
  v2f a; a.x = q.x + e0; a.y = q.y + e1;
  v2f t = xla_tanh2(a);
  acc = fma((double)g.x, (double)t.x, acc);
  acc = fma((double)g.y, (double)t.y, acc);
  v2f b; b.x = q.z + e2; b.y = q.w + e3;
  v2f u = xla_tanh2(b);
  acc = fma((double)g.z, (double)u.x, acc);
  acc = fma((double)g.w, (double)u.y, acc);
}

__device__ __forceinline__ double wave_sum_f64(double v){
  #pragma unroll
  for (int off = 32; off; off >>= 1) v += __shfl_xor(v, off, 64);
  return v;
}

// ---------------- e_g / e_p precompute (runs once) ----------------
__global__ __launch_bounds__(256) void precompute_e_kernel(
    const float* __restrict__ ctx, const float* __restrict__ W,
    const float* __restrict__ bias, float* __restrict__ e_out)
{
#pragma clang fp contract(off)
  __shared__ float Ct[64][65];
  __shared__ float Wt[128][65];
  const int tid = threadIdx.x;
  const int tx = tid & 31;
  const int ty = tid >> 5;
  const size_t r0 = (size_t)blockIdx.x * 64;

  double acc[8][4];
  #pragma unroll
  for (int i=0;i<8;++i){
    #pragma unroll
    for (int j=0;j<4;++j) acc[i][j]=0.0;
  }

  for (int kc=0; kc<2; ++kc){
    for (int idx = tid; idx < 64*64; idx += 256){
      const int row = idx >> 6, col = idx & 63;
      Ct[row][col] = ctx[(r0 + row)*HH + kc*64 + col];
    }
    for (int idx = tid; idx < 128*64; idx += 256){
      const int row = idx >> 6, col = idx & 63;
      Wt[row][col] = W[row*HH + kc*64 + col];
    }
    __syncthreads();
    #pragma unroll 4
    for (int kk=0; kk<64; ++kk){
      float cv[8], wv[4];
      #pragma unroll
      for (int i=0;i<8;++i) cv[i] = Ct[ty + 8*i][kk];
      #pragma unroll
      for (int j=0;j<4;++j) wv[j] = Wt[tx + 32*j][kk];
      #pragma unroll
      for (int i=0;i<8;++i){
        #pragma unroll
        for (int j=0;j<4;++j) acc[i][j] += (double)cv[i] * (double)wv[j];
      }
    }
    __syncthreads();
  }
  #pragma unroll
  for (int i=0;i<8;++i){
    const size_t r = r0 + ty + 8*i;
    const int s  = (int)(r >> 9);
    const int bb = (int)(r & 511);
    float* dst = e_out + ((size_t)bb*SS + s)*HH;
    #pragma unroll
    for (int j=0;j<4;++j){
      const int c = tx + 32*j;
      dst[c] = (float)acc[i][j] + bias[c];
    }
  }
}

// ---------------- weight pack (runs once): transposed + 4-k-packed f32 ----------------
__global__ void pack_weights_kernel(
    const float* __restrict__ Wi, const float* __restrict__ Wh,
    const float* __restrict__ Wqg, const float* __restrict__ Wqp,
    float* __restrict__ WiP, float* __restrict__ WhP,
    float* __restrict__ WqgP, float* __restrict__ WqpP)
{
  const int i = blockIdx.x * blockDim.x + threadIdx.x;
  if (i < G4*EE){
    const int j = i / EE, e = i % EE;
    const size_t d = ((size_t)(e>>2)*G4 + j)*4 + (e&3);
    WiP[d] = Wi[i];
    WhP[d] = Wh[i];
  }
  if (i < HH*HH){
    const int o = i / HH, k = i % HH;
    const size_t d = ((size_t)(k>>2)*HH + o)*4 + (k&3);
    WqgP[d] = Wqg[i];
    WqpP[d] = Wqp[i];
  }
}

// ---------------- fused decode ----------------
// R10 = R9 with the E-phase indexing bug fixed (eEp base had p8E*32 rows built in
// AND the loop index added them again -> wave-groups 1..7 read wrong rows).
// Now eEp = egb + hE (column base) and the loop uses absolute row s0.
// Design: 2 blocks/CU occupancy retry -- LDS ~29KB (no e_s cache; D/E/G stream
// e_g/e_p from global at step-invariant coalesced L3-resident addresses),
// __launch_bounds__(1024,8). Values / chunk boundaries / orders unchanged ->
// bit-identical output.
__global__ __launch_bounds__(1024, 8) void decode_kernel(
    const float* __restrict__ dec0, const float* __restrict__ h0v, const float* __restrict__ c0v,
    const float* __restrict__ WiP, const float* __restrict__ WhP,
    const float* __restrict__ bi, const float* __restrict__ bh,
    const float* __restrict__ WqgP, const float* __restrict__ bqg, const float* __restrict__ vg,
    const float* __restrict__ WqpP, const float* __restrict__ bqp, const float* __restrict__ vp,
    const float* __restrict__ e_g, const float* __restrict__ e_p,
    const float* __restrict__ emb,
    float* __restrict__ probs_out, float* __restrict__ sels_out,
    float* __restrict__ hx_out, float* __restrict__ cx_out)
{
#pragma clang fp contract(off)
  const int b = blockIdx.x;
  const int tid = threadIdx.x;
  const int lane = tid & 63;
  const int w = tid >> 6;            // 16 waves

  __shared__ double parts8[8][258];  // 16.5 KB padded partials
  __shared__ double u64_s[SS];       // softmax#1 output (f64, for E)
  __shared__ float  gates_s[G4];
  __shared__ double dec64_s[EE];     // decoder input (f64, for A)
  __shared__ float  hy_s[HH];        // f32 h (for hx_out)
  __shared__ double hy64_s[HH];      // f64 h (for A-Wh and C)
  __shared__ float  c_s[HH];
  __shared__ double gl64_s[HH];      // f64 g_l (for F)
  __shared__ float  q_s[HH], vg_s[HH], vp_s[HH];
  __shared__ float  bqg_s[HH], bqp_s[HH];
  __shared__ uint32_t keys0_s[TT], keys1_s[TT];
  __shared__ unsigned char mask_s[SS];
  __shared__ float  fred_s[4];
  __shared__ double dred_s[4];
  __shared__ float  amax_v[4];
  __shared__ int    amax_i[4];
  __shared__ int    idx_sh, fin_sh;

  const float* egb = e_g + (size_t)b*SS*HH;
  const float* epb = e_p + (size_t)b*SS*HH;

  // ---- one-time block init ----
  if (tid < HH){
    dec64_s[tid] = (double)dec0[b*EE + tid];
    const float h0f = h0v[b*HH + tid];
    hy_s[tid]  = h0f;
    hy64_s[tid] = (double)h0f;
    c_s[tid]   = c0v[b*HH + tid];
    vg_s[tid]  = vg[tid];
    vp_s[tid]  = vp[tid];
    bqg_s[tid] = bqg[tid];
    bqp_s[tid] = bqp[tid];
  }
  if (tid < SS) mask_s[tid] = 0;
  if (tid < TT){
    uint32_t kk0, kk1;
    threefry2x32(0u, 42u, 0u, (uint32_t)tid, &kk0, &kk1);
    keys0_s[tid] = kk0; keys1_s[tid] = kk1;
  }
  if (tid == 0) fin_sh = 1;
  __syncthreads();

  // D/G thread map: one s-row per lane, quarter selected by wave group
  const int sD  = tid & 255;         // 0..255 (wave = 64 consecutive rows)
  const int q4r = tid >> 8;          // 0..3 (wave-uniform)
  const float4* eDp = (const float4*)(egb + sD*HH + q4r*32);  // step-invariant
  const float4* eGp = (const float4*)(epb + sD*HH + q4r*32);  // step-invariant
  // E map
  const int hE  = tid & 127;
  const int p8E = tid >> 7;
  const float* eEp = egb + hE;       // column base; rows indexed ABSOLUTELY below

  for (int t = 0; t < TT; ++t){
    // ---- A: gates GEMV split across thread halves; activation fused (f64 fma) ----
    double* aux = &parts8[0][0];     // 512 f64 scratch (rows 0-1), free here
    double a0 = 0.0;
    if (tid < 512){
      const float4* Wp = (const float4*)WiP + tid;
      double p0=0.0,p1=0.0,p2=0.0,p3=0.0;
      #pragma unroll 8
      for (int e4=0;e4<32;++e4){
        const float4 wv = Wp[(size_t)e4*G4];
        const double2 d01 = *(const double2*)&dec64_s[e4*4];
        const double2 d23 = *(const double2*)&dec64_s[e4*4+2];
        p0 = fma(d01.x, (double)wv.x, p0);
        p1 = fma(d01.y, (double)wv.y, p1);
        p2 = fma(d23.x, (double)wv.z, p2);
        p3 = fma(d23.y, (double)wv.w, p3);
      }
      a0 = ((p0+p1)+p2)+p3;
    } else {
      const int j = tid - 512;
      const float4* Wp = (const float4*)WhP + j;
      double r0=0.0,r1=0.0,r2=0.0,r3=0.0;
      #pragma unroll 8
      for (int k4=0;k4<32;++k4){
        const float4 wv = Wp[(size_t)k4*G4];
        const double2 h01 = *(const double2*)&hy64_s[k4*4];
        const double2 h23 = *(const double2*)&hy64_s[k4*4+2];
        r0 = fma(h01.x, (double)wv.x, r0);
        r1 = fma(h01.y, (double)wv.y, r1);
        r2 = fma(h23.x, (double)wv.z, r2);
        r3 = fma(h23.y, (double)wv.w, r3);
      }
      aux[j] = ((r0+r1)+r2)+r3;
    }
    __syncthreads();
    if (tid < 512){
      const int j = tid;
      const float g = (float)a0 + bi[j] + (float)aux[j] + bh[j];
      gates_s[j] = ((j >> 7) == 2) ? xla_tanhf(g) : xla_sigmoidf(g);
    }
    __syncthreads();

    // ---- B2: LSTM combine (widen hy once) ----
    if (tid < HH){
      const int h = tid;
      const float cn = gates_s[HH+h]*c_s[h] + gates_s[h]*gates_s[2*HH+h];
      const float hn = gates_s[3*HH+h]*xla_tanhf(cn);
      c_s[h] = cn; hy_s[h] = hn; hy64_s[h] = (double)hn;
    }
    __syncthreads();

    // ---- C: q_g = hy @ Wq_g.T + bq_g (f64 fma; k-order unchanged) ----
    if (tid < 512){
      const int o = tid & 127, qc = tid >> 7;
      const float4* Wc = (const float4*)WqgP + (size_t)qc*8*HH + o;
      double acc = 0.0;
      #pragma unroll
      for (int i8=0;i8<8;++i8){
        const float4 wv = Wc[(size_t)i8*HH];
        const int k = qc*32 + i8*4;
        const double2 h01 = *(const double2*)&hy64_s[k];
        const double2 h23 = *(const double2*)&hy64_s[k+2];
        acc = fma(h01.x, (double)wv.x, acc);
        acc = fma(h01.y, (double)wv.y, acc);
        acc = fma(h23.x, (double)wv.z, acc);
        acc = fma(h23.y, (double)wv.w, acc);
      }
      parts8[qc][o] = acc;
    }
    __syncthreads();
    if (tid < HH)
      q_s[tid] = (float)(((parts8[0][tid]+parts8[1][tid])+parts8[2][tid])+parts8[3][tid]) + bqg_s[tid];
    __syncthreads();

    // ---- D: u_g partials; e_g quarter-row from global (8x float4 upfront, L3-hot);
    //      q/vg broadcast from LDS. Order/boundaries unchanged, bit-identical. ----
    const bool skipRow = (mask_s[sD] != 0);
    if (!skipRow){
      float ev[32];
      #pragma unroll
      for (int m=0;m<8;++m) *(float4*)&ev[m*4] = eDp[m];
      #pragma unroll
      for (int cc=0; cc<2; ++cc){
        const int hb = q4r*32 + cc*16;
        const float4 qa = *(const float4*)&q_s[hb+0];
        const float4 qb = *(const float4*)&q_s[hb+4];
        const float4 qc4= *(const float4*)&q_s[hb+8];
        const float4 qd = *(const float4*)&q_s[hb+12];
        const float4 ga = *(const float4*)&vg_s[hb+0];
        const float4 gb = *(const float4*)&vg_s[hb+4];
        const float4 gc = *(const float4*)&vg_s[hb+8];
        const float4 gd = *(const float4*)&vg_s[hb+12];
        const int eb = cc*16;
        double acc = 0.0;
        quad_acc(acc, qa, ga, ev[eb+0],  ev[eb+1],  ev[eb+2],  ev[eb+3]);
        quad_acc(acc, qb, gb, ev[eb+4],  ev[eb+5],  ev[eb+6],  ev[eb+7]);
        quad_acc(acc, qc4,gc, ev[eb+8],  ev[eb+9],  ev[eb+10], ev[eb+11]);
        quad_acc(acc, qd, gd, ev[eb+12], ev[eb+13], ev[eb+14], ev[eb+15]);
        parts8[q4r*2 + cc][sD] = acc;
      }
    }
    __syncthreads();

    // ---- D combine fused with softmax#1 max ----
    float x1 = 0.0f;
    if (tid < SS){
      if (mask_s[tid]) x1 = NEG_INF_F;
      else {
        double u = 0.0;
        #pragma unroll
        for (int wi=0;wi<8;++wi) u += parts8[wi][tid];
        x1 = (float)u;
      }
      float wm = x1;
      #pragma unroll
      for (int off=32; off; off>>=1) wm = fmaxf(wm, __shfl_xor(wm, off, 64));
      if (lane == 0) fred_s[w] = wm;
    }
    __syncthreads();
    {
      const float m = fmaxf(fmaxf(fred_s[0], fred_s[1]), fmaxf(fred_s[2], fred_s[3]));
      float p = 0.0f;
      if (tid < SS){
        p = mask_s[tid] ? 0.0f : expf(x1 - m);
        const double zs = wave_sum_f64((double)p);
        if (lane == 0) dred_s[w] = zs;
      }
      __syncthreads();
      const float Z = (float)(dred_s[0] + dred_s[1] + dred_s[2] + dred_s[3]);
      if (tid < SS){
        const float av = p / Z;
        u64_s[tid] = (double)av;
      }
    }
    __syncthreads();

    // ---- E: g_l[h] = Σ_s a[s]*e_g[s,h]; e_g rows from global, ABSOLUTE row index ----
    {
      double acc = 0.0;
      #pragma unroll
      for (int g4i=0; g4i<8; ++g4i){
        const int s0 = p8E*32 + g4i*4;
        const float ea = eEp[(size_t)(s0+0)*HH];
        const float eb2= eEp[(size_t)(s0+1)*HH];
        const float ec = eEp[(size_t)(s0+2)*HH];
        const float ed = eEp[(size_t)(s0+3)*HH];
        const double2 ua = *(const double2*)&u64_s[s0];
        const double2 ub = *(const double2*)&u64_s[s0+2];
        acc = fma(ua.x, (double)ea, acc);
        acc = fma(ua.y, (double)eb2, acc);
        acc = fma(ub.x, (double)ec, acc);
        acc = fma(ub.y, (double)ed, acc);
      }
      parts8[p8E][hE] = acc;
    }
    __syncthreads();
    if (tid < HH){
      double g = parts8[0][tid];
      #pragma unroll
      for (int p8=1;p8<8;++p8) g += parts8[p8][tid];
      const float gf = (float)g;
      gl64_s[tid] = (double)gf;   // consumers used (double)(float)g: identical
    }
    __syncthreads();

    // ---- prefetch G's e_p quarter (step-invariant addr, L3-hot; F hides latency) ----
    float evp[32];
    #pragma unroll
    for (int k=0;k<8;++k) *(float4*)&evp[4*k] = eGp[k];

    // ---- F: q_p = g_l @ Wq_p.T + bq_p (f64 fma) ----
    if (tid < 512){
      const int o = tid & 127, qc = tid >> 7;
      const float4* Wc = (const float4*)WqpP + (size_t)qc*8*HH + o;
      double acc = 0.0;
      #pragma unroll
      for (int i8=0;i8<8;++i8){
        const float4 wv = Wc[(size_t)i8*HH];
        const int k = qc*32 + i8*4;
        const double2 g01 = *(const double2*)&gl64_s[k];
        const double2 g23 = *(const double2*)&gl64_s[k+2];
        acc = fma(g01.x, (double)wv.x, acc);
        acc = fma(g01.y, (double)wv.y, acc);
        acc = fma(g23.x, (double)wv.z, acc);
        acc = fma(g23.y, (double)wv.w, acc);
      }
      parts8[qc][o] = acc;
    }
    __syncthreads();
    if (tid < HH)
      q_s[tid] = (float)(((parts8[0][tid]+parts8[1][tid])+parts8[2][tid])+parts8[3][tid]) + bqp_s[tid];
    __syncthreads();

    // ---- G: u_p partials; prefetched e_p, broadcast q/vp (bit-identical chunking) ----
    if (!skipRow){
      #pragma unroll
      for (int cc=0; cc<2; ++cc){
        const int hb = q4r*32 + cc*16;
        const float4 qa = *(const float4*)&q_s[hb+0];
        const float4 qb = *(const float4*)&q_s[hb+4];
        const float4 qc4= *(const float4*)&q_s[hb+8];
        const float4 qd = *(const float4*)&q_s[hb+12];
        const float4 ga = *(const float4*)&vp_s[hb+0];
        const float4 gb = *(const float4*)&vp_s[hb+4];
        const float4 gc = *(const float4*)&vp_s[hb+8];
        const float4 gd = *(const float4*)&vp_s[hb+12];
        const int eb = cc*16;
        double acc = 0.0;
        quad_acc(acc, qa, ga, evp[eb+0],  evp[eb+1],  evp[eb+2],  evp[eb+3]);
        quad_acc(acc, qb, gb, evp[eb+4],  evp[eb+5],  evp[eb+6],  evp[eb+7]);
        quad_acc(acc, qc4,gc, evp[eb+8],  evp[eb+9],  evp[eb+10], evp[eb+11]);
        quad_acc(acc, qd, gd, evp[eb+12], evp[eb+13], evp[eb+14], evp[eb+15]);
        parts8[q4r*2 + cc][sD] = acc;
      }
    }
    __syncthreads();

    float logit_x = NEG_INF_F;
    if (tid < SS){
      if (!mask_s[tid]){
        double u = 0.0;
        #pragma unroll
        for (int wi=0;wi<8;++wi) u += parts8[wi][tid];
        logit_x = 10.0f * xla_tanhf((float)u);
      }
    }

    // ---- softmax #2 -> probs out ----
    {
      const float x = logit_x;
      if (tid < SS){
        float wm = x;
        #pragma unroll
        for (int off=32; off; off>>=1) wm = fmaxf(wm, __shfl_xor(wm, off, 64));
        if (lane == 0) fred_s[w] = wm;
      }
      __syncthreads();
      const float m = fmaxf(fmaxf(fred_s[0], fred_s[1]), fmaxf(fred_s[2], fred_s[3]));
      float p = 0.0f;
      if (tid < SS){
        p = mask_s[tid] ? 0.0f : expf(x - m);
        const double zs = wave_sum_f64((double)p);
        if (lane == 0) dred_s[w] = zs;
      }
      __syncthreads();
      const float Z = (float)(dred_s[0] + dred_s[1] + dred_s[2] + dred_s[3]);
      if (tid < SS) probs_out[((size_t)t*BB + b)*SS + tid] = p / Z;
    }

    // ---- gumbel + argmax + state update ----
    {
      if (tid < SS){
        float y = -3.0e38f;
        if (!mask_s[tid]){
          uint32_t r0, r1;
          threefry2x32(keys0_s[t], keys1_s[t], 0u, (uint32_t)(b*SS + tid), &r0, &r1);
          const uint32_t bits = r0 ^ r1;
          const float f = __uint_as_float((bits >> 9) | 0x3f800000u) - 1.0f;
          const float u01 = fmaxf(TINY_F32, f);
          const float g = -logf(-logf(u01));
          y = logit_x + g;
        }
        int bi_ = tid;
        #pragma unroll
        for (int off=32; off; off>>=1){
          const float oy = __shfl_xor(y, off, 64);
          const int oi = __shfl_xor(bi_, off, 64);
          if (oy > y || (oy == y && oi < bi_)){ y = oy; bi_ = oi; }
        }
        if (lane == 0){ amax_v[w] = y; amax_i[w] = bi_; }
      }
      __syncthreads();
      if (tid == 0){
        float bv = amax_v[0]; int bidx = amax_i[0];
        #pragma unroll
        for (int k=1;k<4;++k){
          if (amax_v[k] > bv || (amax_v[k] == bv && amax_i[k] < bidx)){ bv = amax_v[k]; bidx = amax_i[k]; }
        }
        const int fin = fin_sh;
        const int idx = fin ? bidx : 0;
        sels_out[(size_t)t*BB + b] = (float)idx;
        fin_sh = (fin && idx != 0) ? 1 : 0;
        mask_s[idx] = 1;
        mask_s[0] = 0;
        idx_sh = idx;
      }
      __syncthreads();
      if (tid < EE){
        dec64_s[tid] = (double)emb[((size_t)idx_sh*BB + b)*EE + tid];
      }
    }
    __syncthreads();   // dec64_s/mask_s ready for next step
  }

  // ---- final state write ----
  if (tid < HH){
    hx_out[b*HH + tid] = hy_s[tid];
    cx_out[b*HH + tid] = c_s[tid];
  }
}

__global__ void ws_fail_kernel(float* sels_out){
  if (threadIdx.x == 0 && blockIdx.x == 0) sels_out[0] = -77777.0f;
}

extern "C" void kernel_launch(void* const* d_in, const int* in_sizes, int n_in,
                              void* d_out, int out_size, void* d_ws, size_t ws_size,
                              hipStream_t stream)
{
  const float* decoder_input = (const float*)d_in[0];
  const float* embedded      = (const float*)d_in[1];
  const float* h0            = (const float*)d_in[2];
  const float* c0            = (const float*)d_in[3];
  const float* context       = (const float*)d_in[4];
  const float* Wi            = (const float*)d_in[5];
  const float* bi            = (const float*)d_in[6];
  const float* Wh            = (const float*)d_in[7];
  const float* bh            = (const float*)d_in[8];
  const float* Wq_g          = (const float*)d_in[9];
  const float* bq_g          = (const float*)d_in[10];
  const float* Wref_g        = (const float*)d_in[11];
  const float* bref_g        = (const float*)d_in[12];
  const float* v_g           = (const float*)d_in[13];
  const float* Wq_p          = (const float*)d_in[14];
  const float* bq_p          = (const float*)d_in[15];
  const float* Wref_p        = (const float*)d_in[16];
  const float* bref_p        = (const float*)d_in[17];
  const float* v_p           = (const float*)d_in[18];

  char* ws = (char*)d_ws;
  size_t off = 0;
  auto alloc = [&](size_t bytes) -> void* {
    void* p = ws + off;
    off += (bytes + 255) & ~(size_t)255;
    return p;
  };
  float* e_g  = (float*)alloc((size_t)BB*SS*HH*4);
  float* e_p  = (float*)alloc((size_t)BB*SS*HH*4);
  float* WiP  = (float*)alloc((size_t)EE*G4*4);
  float* WhP  = (float*)alloc((size_t)HH*G4*4);
  float* WqgP = (float*)alloc((size_t)HH*HH*4);
  float* WqpP = (float*)alloc((size_t)HH*HH*4);

  float* probs_out = (float*)d_out;                  // (T,B,S)
  float* sels_out  = probs_out + (size_t)TT*BB*SS;   // (T,B)
  float* hx_out    = sels_out + (size_t)TT*BB;       // (B,H)
  float* cx_out    = hx_out + (size_t)BB*HH;         // (B,H)

  if (off > ws_size){
    ws_fail_kernel<<<1, 64, 0, stream>>>(sels_out);
    return;
  }

  pack_weights_kernel<<<(G4*EE + 255)/256, 256, 0, stream>>>(
      Wi, Wh, Wq_g, Wq_p, WiP, WhP, WqgP, WqpP);
  precompute_e_kernel<<<(SS*BB)/64, 256, 0, stream>>>(context, Wref_g, bref_g, e_g);
  precompute_e_kernel<<<(SS*BB)/64, 256, 0, stream>>>(context, Wref_p, bref_p, e_p);

  decode_kernel<<<BB, 1024, 0, stream>>>(
      decoder_input, h0, c0,
      WiP, WhP, bi, bh,
      WqgP, bq_g, v_g,
      WqpP, bq_p, v_p,
      e_g, e_p, embedded,
      probs_out, sels_out, hx_out, cx_out);
}

// Round 11
// 8020.842 us; speedup vs baseline: 1.4081x; 1.4081x over previous
//
#include <hip/hip_runtime.h>
#include <stdint.h>

// Problem dims (fixed by reference)
#define BB 512      // batch
#define SS 256      // seq
#define EE 128      // embed
#define HH 128      // hidden
#define TT 128      // decode steps
#define G4 512      // 4*H

#define NEG_INF_F (-1e30f)
#define TINY_F32  1.17549435e-38f

typedef float v2f __attribute__((ext_vector_type(2)));

// ---------------- threefry2x32 (JAX-exact, 20 rounds) ----------------
__device__ __forceinline__ uint32_t rotl32(uint32_t v, int r){ return (v<<r)|(v>>(32-r)); }

__device__ __forceinline__ void threefry2x32(uint32_t k0, uint32_t k1,
                                             uint32_t c0, uint32_t c1,
                                             uint32_t* o0, uint32_t* o1){
  uint32_t ks2 = k0 ^ k1 ^ 0x1BD11BDAu;
  uint32_t x0 = c0 + k0;
  uint32_t x1 = c1 + k1;
#define TF_R(rr) { x0 += x1; x1 = rotl32(x1, rr); x1 ^= x0; }
  TF_R(13) TF_R(15) TF_R(26) TF_R(6)
  x0 += k1; x1 += ks2 + 1u;
  TF_R(17) TF_R(29) TF_R(16) TF_R(24)
  x0 += ks2; x1 += k0 + 2u;
  TF_R(13) TF_R(15) TF_R(26) TF_R(6)
  x0 += k0; x1 += k1 + 3u;
  TF_R(17) TF_R(29) TF_R(16) TF_R(24)
  x0 += k1; x1 += ks2 + 4u;
  TF_R(13) TF_R(15) TF_R(26) TF_R(6)
  x0 += ks2; x1 += k0 + 5u;
#undef TF_R
  *o0 = x0; *o1 = x1;
}

// ---------------- XLA CPU f32 tanh expansion (scalar) ----------------
__device__ __forceinline__ float xla_tanhf(float x){
#pragma clang fp contract(off)
  float ax = fabsf(x);
  float xc = fminf(fmaxf(x, -9.0f), 9.0f);
  float x2 = xc*xc;
  float num = -2.76076847742355e-16f;
  num = x2*num + 2.00018790482477e-13f;
  num = x2*num + -8.60467152213735e-11f;
  num = x2*num + 5.12229709037114e-08f;
  num = x2*num + 1.48572235717979e-05f;
  num = x2*num + 6.37261928875436e-04f;
  num = x2*num + 4.89352455891786e-03f;
  num = xc*num;
  float den = 1.19825839466702e-06f;
  den = x2*den + 1.18534705686654e-04f;
  den = x2*den + 2.26843463243900e-03f;
  den = x2*den + 4.89352518554385e-03f;
  return (ax < 4e-4f) ? x : (num/den);
}

__device__ __forceinline__ float xla_sigmoidf(float x){
#pragma clang fp contract(off)
  return 0.5f + 0.5f * xla_tanhf(0.5f * x);
}

// ---------------- packed-pair tanh: identical per-element IEEE ops ----------------
__device__ __forceinline__ v2f splat2(float c){ v2f r; r.x = c; r.y = c; return r; }

__device__ __forceinline__ v2f xla_tanh2(v2f x){
#pragma clang fp contract(off)
  v2f xc;
  xc.x = fminf(fmaxf(x.x, -9.0f), 9.0f);
  xc.y = fminf(fmaxf(x.y, -9.0f), 9.0f);
  v2f x2 = xc*xc;
  v2f num = splat2(-2.76076847742355e-16f);
  num = x2*num + splat2( 2.00018790482477e-13f);
  num = x2*num + splat2(-8.60467152213735e-11f);
  num = x2*num + splat2( 5.12229709037114e-08f);
  num = x2*num + splat2( 1.48572235717979e-05f);
  num = x2*num + splat2( 6.37261928875436e-04f);
  num = x2*num + splat2( 4.89352455891786e-03f);
  num = xc*num;
  v2f den = splat2( 1.19825839466702e-06f);
  den = x2*den + splat2( 1.18534705686654e-04f);
  den = x2*den + splat2( 2.26843463243900e-03f);
  den = x2*den + splat2( 4.89352518554385e-03f);
  v2f r;
  r.x = num.x/den.x;
  r.y = num.y/den.y;
  r.x = (fabsf(x.x) < 4e-4f) ? x.x : r.x;
  r.y = (fabsf(x.y) < 4e-4f) ? x.y : r.y;
  return r;
}

// 4 elements. f64 accumulate via explicit fma(): the products are f32-origin
// (24b x 24b mantissa = 48b < 53b) -> v_mul_f64 would be EXACT -> fma == mul+add
// bit-identically, at half the f64 issue slots. Order i,i+1,i+2,i+3 unchanged.
__device__ __forceinline__ void quad_acc(double& acc, const float4 q, const float4 g,
                                         float e0, float e1, float e2, float e3){
#pragma clang fp contract(off)
  v2f a; a.x = q.x + e0; a.y = q.y + e1;
  v2f t = xla_tanh2(a);
  acc = fma((double)g.x, (double)t.x, acc);
  acc = fma((double)g.y, (double)t.y, acc);
  v2f b; b.x = q.z + e2; b.y = q.w + e3;
  v2f u = xla_tanh2(b);
  acc = fma((double)g.z, (double)u.x, acc);
  acc = fma((double)g.w, (double)u.y, acc);
}

__device__ __forceinline__ double wave_sum_f64(double v){
  #pragma unroll
  for (int off = 32; off; off >>= 1) v += __shfl_xor(v, off, 64);
  return v;
}

// ---------------- e_g / e_p precompute (runs once) ----------------
__global__ __launch_bounds__(256) void precompute_e_kernel(
    const float* __restrict__ ctx, const float* __restrict__ W,
    const float* __restrict__ bias, float* __restrict__ e_out)
{
#pragma clang fp contract(off)
  __shared__ float Ct[64][65];
  __shared__ float Wt[128][65];
  const int tid = threadIdx.x;
  const int tx = tid & 31;
  const int ty = tid >> 5;
  const size_t r0 = (size_t)blockIdx.x * 64;

  double acc[8][4];
  #pragma unroll
  for (int i=0;i<8;++i){
    #pragma unroll
    for (int j=0;j<4;++j) acc[i][j]=0.0;
  }

  for (int kc=0; kc<2; ++kc){
    for (int idx = tid; idx < 64*64; idx += 256){
      const int row = idx >> 6, col = idx & 63;
      Ct[row][col] = ctx[(r0 + row)*HH + kc*64 + col];
    }
    for (int idx = tid; idx < 128*64; idx += 256){
      const int row = idx >> 6, col = idx & 63;
      Wt[row][col] = W[row*HH + kc*64 + col];
    }
    __syncthreads();
    #pragma unroll 4
    for (int kk=0; kk<64; ++kk){
      float cv[8], wv[4];
      #pragma unroll
      for (int i=0;i<8;++i) cv[i] = Ct[ty + 8*i][kk];
      #pragma unroll
      for (int j=0;j<4;++j) wv[j] = Wt[tx + 32*j][kk];
      #pragma unroll
      for (int i=0;i<8;++i){
        #pragma unroll
        for (int j=0;j<4;++j) acc[i][j] += (double)cv[i] * (double)wv[j];
      }
    }
    __syncthreads();
  }
  #pragma unroll
  for (int i=0;i<8;++i){
    const size_t r = r0 + ty + 8*i;
    const int s  = (int)(r >> 9);
    const int bb = (int)(r & 511);
    float* dst = e_out + ((size_t)bb*SS + s)*HH;
    #pragma unroll
    for (int j=0;j<4;++j){
      const int c = tx + 32*j;
      dst[c] = (float)acc[i][j] + bias[c];
    }
  }
}

// ---------------- weight pack (runs once): transposed + 4-k-packed f32 ----------------
__global__ void pack_weights_kernel(
    const float* __restrict__ Wi, const float* __restrict__ Wh,
    const float* __restrict__ Wqg, const float* __restrict__ Wqp,
    float* __restrict__ WiP, float* __restrict__ WhP,
    float* __restrict__ WqgP, float* __restrict__ WqpP)
{
  const int i = blockIdx.x * blockDim.x + threadIdx.x;
  if (i < G4*EE){
    const int j = i / EE, e = i % EE;
    const size_t d = ((size_t)(e>>2)*G4 + j)*4 + (e&3);
    WiP[d] = Wi[i];
    WhP[d] = Wh[i];
  }
  if (i < HH*HH){
    const int o = i / HH, k = i % HH;
    const size_t d = ((size_t)(k>>2)*HH + o)*4 + (k&3);
    WqgP[d] = Wqg[i];
    WqpP[d] = Wqp[i];
  }
}

// ---------------- fused decode ----------------
// R11 = exact revert to R8 (best verified: 8,043 us). R10's 2-blocks/CU experiment
// conclusively failed: 90% occupancy but 20.7 GB L2-miss e-stream traffic ->
// latency-bound (VALUBusy 41%). R8's configuration is the capacity sweet spot:
// e_g in 128KB LDS (swizzled row-per-lane D reads), e_p via per-step prefetch
// that stays L2-resident (32 blocks/XCD x 128KB slice = 4MB = per-XCD L2).
// All values / chunk boundaries / orders unchanged -> bit-identical output.
__global__ __launch_bounds__(1024, 4) void decode_kernel(
    const float* __restrict__ dec0, const float* __restrict__ h0v, const float* __restrict__ c0v,
    const float* __restrict__ WiP, const float* __restrict__ WhP,
    const float* __restrict__ bi, const float* __restrict__ bh,
    const float* __restrict__ WqgP, const float* __restrict__ bqg, const float* __restrict__ vg,
    const float* __restrict__ WqpP, const float* __restrict__ bqp, const float* __restrict__ vp,
    const float* __restrict__ e_g, const float* __restrict__ e_p,
    const float* __restrict__ emb,
    float* __restrict__ probs_out, float* __restrict__ sels_out,
    float* __restrict__ hx_out, float* __restrict__ cx_out)
{
#pragma clang fp contract(off)
  const int b = blockIdx.x;
  const int tid = threadIdx.x;
  const int lane = tid & 63;
  const int w = tid >> 6;            // 16 waves

  __shared__ float  e_s[SS][HH];     // 128 KB e_g, XOR-swizzled 16B chunks within each row
  __shared__ double parts8[8][258];  // 16.5 KB padded partials
  __shared__ double u64_s[SS];       // softmax#1 output (f64, for E)
  __shared__ float  gates_s[G4];
  __shared__ double dec64_s[EE];     // decoder input (f64, for A)
  __shared__ float  hy_s[HH];        // f32 h (for hx_out)
  __shared__ double hy64_s[HH];      // f64 h (for A-Wh and C)
  __shared__ float  c_s[HH];
  __shared__ double gl64_s[HH];      // f64 g_l (for F); value = (double)(float)g
  __shared__ float  q_s[HH], vg_s[HH], vp_s[HH];
  __shared__ float  bqg_s[HH], bqp_s[HH];
  __shared__ uint32_t keys0_s[TT], keys1_s[TT];
  __shared__ unsigned char mask_s[SS];
  __shared__ float  fred_s[4];
  __shared__ double dred_s[4];
  __shared__ float  amax_v[4];
  __shared__ int    amax_i[4];
  __shared__ int    idx_sh, fin_sh;

  const float* egb = e_g + (size_t)b*SS*HH;
  const float* epb = e_p + (size_t)b*SS*HH;

  // ---- one-time block init ----
  if (tid < HH){
    dec64_s[tid] = (double)dec0[b*EE + tid];
    const float h0f = h0v[b*HH + tid];
    hy_s[tid]  = h0f;
    hy64_s[tid] = (double)h0f;
    c_s[tid]   = c0v[b*HH + tid];
    vg_s[tid]  = vg[tid];
    vp_s[tid]  = vp[tid];
    bqg_s[tid] = bqg[tid];
    bqp_s[tid] = bqp[tid];
  }
  if (tid < SS) mask_s[tid] = 0;
  if (tid < TT){
    uint32_t kk0, kk1;
    threefry2x32(0u, 42u, 0u, (uint32_t)tid, &kk0, &kk1);
    keys0_s[tid] = kk0; keys1_s[tid] = kk1;
  }
  if (tid == 0) fin_sh = 1;
  // stage e_g into LDS with 16B-chunk XOR swizzle: chunk c4 of row r stored at c4^(r&7)
  for (int idx = tid; idx < SS*32; idx += 1024){
    const int r  = idx >> 5;
    const int c4 = idx & 31;
    *(float4*)&e_s[r][(c4 ^ (r & 7)) << 2] = ((const float4*)egb)[idx];
  }
  __syncthreads();

  // D/G thread map: one s-row per lane, quarter selected by wave group
  const int sD  = tid & 255;         // 0..255 (wave = 64 consecutive rows)
  const int q4r = tid >> 8;          // 0..3 (wave-uniform)
  const float4* eGp = (const float4*)(epb + sD*HH + q4r*32);  // step-invariant
  // E map
  const int hE  = tid & 127;
  const int p8E = tid >> 7;
  const int h4E = hE >> 2, hmE = hE & 3;

  for (int t = 0; t < TT; ++t){
    // ---- A: gates GEMV split across thread halves; activation fused (f64 fma) ----
    double* aux = &parts8[0][0];     // 512 f64 scratch (rows 0-1), free here
    double a0 = 0.0;
    if (tid < 512){
      const float4* Wp = (const float4*)WiP + tid;
      double p0=0.0,p1=0.0,p2=0.0,p3=0.0;
      #pragma unroll 8
      for (int e4=0;e4<32;++e4){
        const float4 wv = Wp[(size_t)e4*G4];
        const double2 d01 = *(const double2*)&dec64_s[e4*4];
        const double2 d23 = *(const double2*)&dec64_s[e4*4+2];
        p0 = fma(d01.x, (double)wv.x, p0);
        p1 = fma(d01.y, (double)wv.y, p1);
        p2 = fma(d23.x, (double)wv.z, p2);
        p3 = fma(d23.y, (double)wv.w, p3);
      }
      a0 = ((p0+p1)+p2)+p3;
    } else {
      const int j = tid - 512;
      const float4* Wp = (const float4*)WhP + j;
      double r0=0.0,r1=0.0,r2=0.0,r3=0.0;
      #pragma unroll 8
      for (int k4=0;k4<32;++k4){
        const float4 wv = Wp[(size_t)k4*G4];
        const double2 h01 = *(const double2*)&hy64_s[k4*4];
        const double2 h23 = *(const double2*)&hy64_s[k4*4+2];
        r0 = fma(h01.x, (double)wv.x, r0);
        r1 = fma(h01.y, (double)wv.y, r1);
        r2 = fma(h23.x, (double)wv.z, r2);
        r3 = fma(h23.y, (double)wv.w, r3);
      }
      aux[j] = ((r0+r1)+r2)+r3;
    }
    __syncthreads();
    if (tid < 512){
      const int j = tid;
      const float g = (float)a0 + bi[j] + (float)aux[j] + bh[j];
      gates_s[j] = ((j >> 7) == 2) ? xla_tanhf(g) : xla_sigmoidf(g);
    }
    __syncthreads();

    // ---- B2: LSTM combine (widen hy once) ----
    if (tid < HH){
      const int h = tid;
      const float cn = gates_s[HH+h]*c_s[h] + gates_s[h]*gates_s[2*HH+h];
      const float hn = gates_s[3*HH+h]*xla_tanhf(cn);
      c_s[h] = cn; hy_s[h] = hn; hy64_s[h] = (double)hn;
    }
    __syncthreads();

    // ---- C: q_g = hy @ Wq_g.T + bq_g (f64 fma; k-order unchanged) ----
    if (tid < 512){
      const int o = tid & 127, qc = tid >> 7;
      const float4* Wc = (const float4*)WqgP + (size_t)qc*8*HH + o;
      double acc = 0.0;
      #pragma unroll
      for (int i8=0;i8<8;++i8){
        const float4 wv = Wc[(size_t)i8*HH];
        const int k = qc*32 + i8*4;
        const double2 h01 = *(const double2*)&hy64_s[k];
        const double2 h23 = *(const double2*)&hy64_s[k+2];
        acc = fma(h01.x, (double)wv.x, acc);
        acc = fma(h01.y, (double)wv.y, acc);
        acc = fma(h23.x, (double)wv.z, acc);
        acc = fma(h23.y, (double)wv.w, acc);
      }
      parts8[qc][o] = acc;
    }
    __syncthreads();
    if (tid < HH)
      q_s[tid] = (float)(((parts8[0][tid]+parts8[1][tid])+parts8[2][tid])+parts8[3][tid]) + bqg_s[tid];
    __syncthreads();

    // ---- D: u_g partials; e from swizzled LDS (b128 row-per-lane); broadcast q/vg ----
    const bool skipRow = (mask_s[sD] != 0);
    if (!skipRow){
      float ev[32];
      #pragma unroll
      for (int m=0;m<8;++m){
        const int c4 = ((q4r<<3) + m) ^ (sD & 7);
        *(float4*)&ev[m*4] = *(const float4*)&e_s[sD][c4<<2];
      }
      #pragma unroll
      for (int cc=0; cc<2; ++cc){
        const int hb = q4r*32 + cc*16;
        const float4 qa = *(const float4*)&q_s[hb+0];
        const float4 qb = *(const float4*)&q_s[hb+4];
        const float4 qc4= *(const float4*)&q_s[hb+8];
        const float4 qd = *(const float4*)&q_s[hb+12];
        const float4 ga = *(const float4*)&vg_s[hb+0];
        const float4 gb = *(const float4*)&vg_s[hb+4];
        const float4 gc = *(const float4*)&vg_s[hb+8];
        const float4 gd = *(const float4*)&vg_s[hb+12];
        const int eb = cc*16;
        double acc = 0.0;
        quad_acc(acc, qa, ga, ev[eb+0],  ev[eb+1],  ev[eb+2],  ev[eb+3]);
        quad_acc(acc, qb, gb, ev[eb+4],  ev[eb+5],  ev[eb+6],  ev[eb+7]);
        quad_acc(acc, qc4,gc, ev[eb+8],  ev[eb+9],  ev[eb+10], ev[eb+11]);
        quad_acc(acc, qd, gd, ev[eb+12], ev[eb+13], ev[eb+14], ev[eb+15]);
        parts8[q4r*2 + cc][sD] = acc;
      }
    }
    __syncthreads();

    // ---- D combine fused with softmax#1 max ----
    float x1 = 0.0f;
    if (tid < SS){
      if (mask_s[tid]) x1 = NEG_INF_F;
      else {
        double u = 0.0;
        #pragma unroll
        for (int wi=0;wi<8;++wi) u += parts8[wi][tid];
        x1 = (float)u;
      }
      float wm = x1;
      #pragma unroll
      for (int off=32; off; off>>=1) wm = fmaxf(wm, __shfl_xor(wm, off, 64));
      if (lane == 0) fred_s[w] = wm;
    }
    __syncthreads();
    {
      const float m = fmaxf(fmaxf(fred_s[0], fred_s[1]), fmaxf(fred_s[2], fred_s[3]));
      float p = 0.0f;
      if (tid < SS){
        p = mask_s[tid] ? 0.0f : expf(x1 - m);
        const double zs = wave_sum_f64((double)p);
        if (lane == 0) dred_s[w] = zs;
      }
      __syncthreads();
      const float Z = (float)(dred_s[0] + dred_s[1] + dred_s[2] + dred_s[3]);
      if (tid < SS){
        const float av = p / Z;
        u64_s[tid] = (double)av;
      }
    }
    __syncthreads();

    // ---- E: g_l[h] = Σ_s a[s]*e_g[s,h] from swizzled LDS (f64 fma) ----
    {
      double acc = 0.0;
      #pragma unroll
      for (int g4i=0; g4i<8; ++g4i){
        const int s0 = p8E*32 + g4i*4;
        const double2 ua = *(const double2*)&u64_s[s0];
        const double2 ub = *(const double2*)&u64_s[s0+2];
        acc = fma(ua.x, (double)e_s[s0+0][((h4E ^ ((s0+0)&7))<<2) | hmE], acc);
        acc = fma(ua.y, (double)e_s[s0+1][((h4E ^ ((s0+1)&7))<<2) | hmE], acc);
        acc = fma(ub.x, (double)e_s[s0+2][((h4E ^ ((s0+2)&7))<<2) | hmE], acc);
        acc = fma(ub.y, (double)e_s[s0+3][((h4E ^ ((s0+3)&7))<<2) | hmE], acc);
      }
      parts8[p8E][hE] = acc;
    }
    __syncthreads();
    if (tid < HH){
      double g = parts8[0][tid];
      #pragma unroll
      for (int p8=1;p8<8;++p8) g += parts8[p8][tid];
      const float gf = (float)g;
      gl64_s[tid] = (double)gf;   // consumers used (double)(float)g: identical
    }
    __syncthreads();

    // ---- prefetch G's e_p quarter (step-invariant addr, L2-hot; F hides latency) ----
    float evp[32];
    #pragma unroll
    for (int k=0;k<8;++k) *(float4*)&evp[4*k] = eGp[k];

    // ---- F: q_p = g_l @ Wq_p.T + bq_p (f64 fma) ----
    if (tid < 512){
      const int o = tid & 127, qc = tid >> 7;
      const float4* Wc = (const float4*)WqpP + (size_t)qc*8*HH + o;
      double acc = 0.0;
      #pragma unroll
      for (int i8=0;i8<8;++i8){
        const float4 wv = Wc[(size_t)i8*HH];
        const int k = qc*32 + i8*4;
        const double2 g01 = *(const double2*)&gl64_s[k];
        const double2 g23 = *(const double2*)&gl64_s[k+2];
        acc = fma(g01.x, (double)wv.x, acc);
        acc = fma(g01.y, (double)wv.y, acc);
        acc = fma(g23.x, (double)wv.z, acc);
        acc = fma(g23.y, (double)wv.w, acc);
      }
      parts8[qc][o] = acc;
    }
    __syncthreads();
    if (tid < HH)
      q_s[tid] = (float)(((parts8[0][tid]+parts8[1][tid])+parts8[2][tid])+parts8[3][tid]) + bqp_s[tid];
    __syncthreads();

    // ---- G: u_p partials; prefetched e_p, broadcast q/vp (bit-identical chunking) ----
    if (!skipRow){
      #pragma unroll
      for (int cc=0; cc<2; ++cc){
        const int hb = q4r*32 + cc*16;
        const float4 qa = *(const float4*)&q_s[hb+0];
        const float4 qb = *(const float4*)&q_s[hb+4];
        const float4 qc4= *(const float4*)&q_s[hb+8];
        const float4 qd = *(const float4*)&q_s[hb+12];
        const float4 ga = *(const float4*)&vp_s[hb+0];
        const float4 gb = *(const float4*)&vp_s[hb+4];
        const float4 gc = *(const float4*)&vp_s[hb+8];
        const float4 gd = *(const float4*)&vp_s[hb+12];
        const int eb = cc*16;
        double acc = 0.0;
        quad_acc(acc, qa, ga, evp[eb+0],  evp[eb+1],  evp[eb+2],  evp[eb+3]);
        quad_acc(acc, qb, gb, evp[eb+4],  evp[eb+5],  evp[eb+6],  evp[eb+7]);
        quad_acc(acc, qc4,gc, evp[eb+8],  evp[eb+9],  evp[eb+10], evp[eb+11]);
        quad_acc(acc, qd, gd, evp[eb+12], evp[eb+13], evp[eb+14], evp[eb+15]);
        parts8[q4r*2 + cc][sD] = acc;
      }
    }
    __syncthreads();

    float logit_x = NEG_INF_F;
    if (tid < SS){
      if (!mask_s[tid]){
        double u = 0.0;
        #pragma unroll
        for (int wi=0;wi<8;++wi) u += parts8[wi][tid];
        logit_x = 10.0f * xla_tanhf((float)u);
      }
    }

    // ---- softmax #2 -> probs out ----
    {
      const float x = logit_x;
      if (tid < SS){
        float wm = x;
        #pragma unroll
        for (int off=32; off; off>>=1) wm = fmaxf(wm, __shfl_xor(wm, off, 64));
        if (lane == 0) fred_s[w] = wm;
      }
      __syncthreads();
      const float m = fmaxf(fmaxf(fred_s[0], fred_s[1]), fmaxf(fred_s[2], fred_s[3]));
      float p = 0.0f;
      if (tid < SS){
        p = mask_s[tid] ? 0.0f : expf(x - m);
        const double zs = wave_sum_f64((double)p);
        if (lane == 0) dred_s[w] = zs;
      }
      __syncthreads();
      const float Z = (float)(dred_s[0] + dred_s[1] + dred_s[2] + dred_s[3]);
      if (tid < SS) probs_out[((size_t)t*BB + b)*SS + tid] = p / Z;
    }

    // ---- gumbel + argmax + state update ----
    {
      if (tid < SS){
        float y = -3.0e38f;
        if (!mask_s[tid]){
          uint32_t r0, r1;
          threefry2x32(keys0_s[t], keys1_s[t], 0u, (uint32_t)(b*SS + tid), &r0, &r1);
          const uint32_t bits = r0 ^ r1;
          const float f = __uint_as_float((bits >> 9) | 0x3f800000u) - 1.0f;
          const float u01 = fmaxf(TINY_F32, f);
          const float g = -logf(-logf(u01));
          y = logit_x + g;
        }
        int bi_ = tid;
        #pragma unroll
        for (int off=32; off; off>>=1){
          const float oy = __shfl_xor(y, off, 64);
          const int oi = __shfl_xor(bi_, off, 64);
          if (oy > y || (oy == y && oi < bi_)){ y = oy; bi_ = oi; }
        }
        if (lane == 0){ amax_v[w] = y; amax_i[w] = bi_; }
      }
      __syncthreads();
      if (tid == 0){
        float bv = amax_v[0]; int bidx = amax_i[0];
        #pragma unroll
        for (int k=1;k<4;++k){
          if (amax_v[k] > bv || (amax_v[k] == bv && amax_i[k] < bidx)){ bv = amax_v[k]; bidx = amax_i[k]; }
        }
        const int fin = fin_sh;
        const int idx = fin ? bidx : 0;
        sels_out[(size_t)t*BB + b] = (float)idx;
        fin_sh = (fin && idx != 0) ? 1 : 0;
        mask_s[idx] = 1;
        mask_s[0] = 0;
        idx_sh = idx;
      }
      __syncthreads();
      if (tid < EE){
        dec64_s[tid] = (double)emb[((size_t)idx_sh*BB + b)*EE + tid];
      }
    }
    __syncthreads();   // dec64_s/mask_s ready for next step
  }

  // ---- final state write ----
  if (tid < HH){
    hx_out[b*HH + tid] = hy_s[tid];
    cx_out[b*HH + tid] = c_s[tid];
  }
}

__global__ void ws_fail_kernel(float* sels_out){
  if (threadIdx.x == 0 && blockIdx.x == 0) sels_out[0] = -77777.0f;
}

extern "C" void kernel_launch(void* const* d_in, const int* in_sizes, int n_in,
                              void* d_out, int out_size, void* d_ws, size_t ws_size,
                              hipStream_t stream)
{
  const float* decoder_input = (const float*)d_in[0];
  const float* embedded      = (const float*)d_in[1];
  const float* h0            = (const float*)d_in[2];
  const float* c0            = (const float*)d_in[3];
  const float* context       = (const float*)d_in[4];
  const float* Wi            = (const float*)d_in[5];
  const float* bi            = (const float*)d_in[6];
  const float* Wh            = (const float*)d_in[7];
  const float* bh            = (const float*)d_in[8];
  const float* Wq_g          = (const float*)d_in[9];
  const float* bq_g          = (const float*)d_in[10];
  const float* Wref_g        = (const float*)d_in[11];
  const float* bref_g        = (const float*)d_in[12];
  const float* v_g           = (const float*)d_in[13];
  const float* Wq_p          = (const float*)d_in[14];
  const float* bq_p          = (const float*)d_in[15];
  const float* Wref_p        = (const float*)d_in[16];
  const float* bref_p        = (const float*)d_in[17];
  const float* v_p           = (const float*)d_in[18];

  char* ws = (char*)d_ws;
  size_t off = 0;
  auto alloc = [&](size_t bytes) -> void* {
    void* p = ws + off;
    off += (bytes + 255) & ~(size_t)255;
    return p;
  };
  float* e_g  = (float*)alloc((size_t)BB*SS*HH*4);
  float* e_p  = (float*)alloc((size_t)BB*SS*HH*4);
  float* WiP  = (float*)alloc((size_t)EE*G4*4);
  float* WhP  = (float*)alloc((size_t)HH*G4*4);
  float* WqgP = (float*)alloc((size_t)HH*HH*4);
  float* WqpP = (float*)alloc((size_t)HH*HH*4);

  float* probs_out = (float*)d_out;                  // (T,B,S)
  float* sels_out  = probs_out + (size_t)TT*BB*SS;   // (T,B)
  float* hx_out    = sels_out + (size_t)TT*BB;       // (B,H)
  float* cx_out    = hx_out + (size_t)BB*HH;         // (B,H)

  if (off > ws_size){
    ws_fail_kernel<<<1, 64, 0, stream>>>(sels_out);
    return;
  }

  pack_weights_kernel<<<(G4*EE + 255)/256, 256, 0, stream>>>(
      Wi, Wh, Wq_g, Wq_p, WiP, WhP, WqgP, WqpP);
  precompute_e_kernel<<<(SS*BB)/64, 256, 0, stream>>>(context, Wref_g, bref_g, e_g);
  precompute_e_kernel<<<(SS*BB)/64, 256, 0, stream>>>(context, Wref_p, bref_p, e_p);

  decode_kernel<<<BB, 1024, 0, stream>>>(
      decoder_input, h0, c0,
      WiP, WhP, bi, bh,
      WqgP, bq_g, v_g,
      WqpP, bq_p, v_p,
      e_g, e_p, embedded,
      probs_out, sels_out, hx_out, cx_out);
}